// Round 8
// baseline (239.262 us; speedup 1.0000x reference)
//
#include <hip/hip_runtime.h>
#include <cstddef>
#include <cstdint>

typedef __attribute__((ext_vector_type(8))) short bf16x8;
typedef __attribute__((ext_vector_type(4))) float f32x4;

constexpr int BN    = 512;    // nodes per bucket
constexpr int CAPB  = 4096;   // per-bucket store capacity (mean 3265, +14 sigma)
constexpr int CHUNK = 4096;   // edges per bin block

__device__ __forceinline__ unsigned short tobf16(float f) {
    unsigned int u = __float_as_uint(f);
    u += 0x7fffu + ((u >> 16) & 1u);   // round to nearest even
    return (unsigned short)(u >> 16);
}
__device__ __forceinline__ float blo(unsigned int u) { return __uint_as_float(u << 16); }
__device__ __forceinline__ float bhi(unsigned int u) { return __uint_as_float(u & 0xffff0000u); }
__device__ __forceinline__ unsigned int pack2(float lo, float hi) {
    return (unsigned int)tobf16(lo) | ((unsigned int)tobf16(hi) << 16);
}
// a[k] += s * row[k]
__device__ __forceinline__ void acc8f(float* a, uint4 v, float s) {
    a[0] = fmaf(s, blo(v.x), a[0]); a[1] = fmaf(s, bhi(v.x), a[1]);
    a[2] = fmaf(s, blo(v.y), a[2]); a[3] = fmaf(s, bhi(v.y), a[3]);
    a[4] = fmaf(s, blo(v.z), a[4]); a[5] = fmaf(s, bhi(v.z), a[5]);
    a[6] = fmaf(s, blo(v.w), a[6]); a[7] = fmaf(s, bhi(v.w), a[7]);
}
__device__ __forceinline__ bf16x8 cvt8(float4 f0, float4 f1) {
    bf16x8 v;
    v[0] = (short)tobf16(f0.x); v[1] = (short)tobf16(f0.y);
    v[2] = (short)tobf16(f0.z); v[3] = (short)tobf16(f0.w);
    v[4] = (short)tobf16(f1.x); v[5] = (short)tobf16(f1.y);
    v[6] = (short)tobf16(f1.z); v[7] = (short)tobf16(f1.w);
    return v;
}

// ---------------- fused: edge binning + gemm1 (no dinv) ----------------
// Bin branch: LDS counting-sort by bucket -> coalesced run-writes to store.
// GEMM branch: A direct global->reg; Bs staged inline from W1 f32 (L2-hit,
// transpose-convert during staging -> no init kernel, no W1T round-trip);
// swapped-operand MFMA, packed uint2 epilogue.

__global__ __launch_bounds__(256)
void bin_gemm1_k(const float* __restrict__ x, const float* __restrict__ W1,
                 unsigned short* __restrict__ hs1, int M,
                 const int* __restrict__ esrc, const int* __restrict__ edst,
                 int* __restrict__ cursor, int* __restrict__ store, int E,
                 int nbin, int nbuck) {
    __shared__ __align__(16) unsigned char smem[34816];
    int b = blockIdx.x, t = threadIdx.x;

    if (b < nbin) {
        // ---- bin branch: histogram -> scan -> LDS sort -> coalesced store ----
        int* sorted = (int*)smem;                   // [4096] 16KB
        int* bkt    = (int*)(smem + 16384);         // [4096] 16KB
        int* comb   = (int*)(smem + 32768);         // [256]  hist -> combined base
        int* ps     = (int*)(smem + 33792);         // [256]  scan -> excl

        comb[t] = 0;                                // hist
        __syncthreads();
        int base = b * CHUNK;
        int nloc = min(CHUNK, E - base);
        int lh[16], bk_[16], pk_[16];
#pragma unroll
        for (int j = 0; j < 16; ++j) {
            int i = j * 256 + t;
            if (i < nloc) {
                int s = esrc[base + i], d = edst[base + i];
                bk_[j] = d >> 9;
                pk_[j] = (s << 9) | (d & (BN - 1));
                lh[j] = atomicAdd(&comb[bk_[j]], 1);
            }
        }
        __syncthreads();
        int hv = comb[t];
        ps[t] = hv;
        __syncthreads();
        for (int off = 1; off < 256; off <<= 1) {
            int v = (t >= off) ? ps[t - off] : 0;
            __syncthreads();
            ps[t] += v;
            __syncthreads();
        }
        int excl = ps[t] - hv;
        ps[t] = excl;                               // own-slot rewrite, no race
        int g = 0;
        if (t < nbuck && hv) g = atomicAdd(&cursor[t], hv);
        comb[t] = t * CAPB + g - excl;              // store base minus local base
        __syncthreads();
#pragma unroll
        for (int j = 0; j < 16; ++j) {
            int i = j * 256 + t;
            if (i < nloc) {
                int lp = ps[bk_[j]] + lh[j];
                sorted[lp] = pk_[j];
                bkt[lp] = bk_[j];
            }
        }
        __syncthreads();
#pragma unroll
        for (int j = 0; j < 16; ++j) {
            int i = j * 256 + t;
            if (i < nloc) {
                int bk = bkt[i];
                int idx = comb[bk] + i;             // consecutive i -> consecutive idx per bucket run
                if (idx - bk * CAPB < CAPB) store[idx] = sorted[i];
            }
        }
        return;
    }

    // ---- gemm1 branch ----
    unsigned short* Bs = (unsigned short*)smem;             // 128*136 bf16
    const int rowBase = (b - nbin) * 128;

    const int lane = t & 63;
    const int w = t >> 6;
    const int l15 = lane & 15;
    const int quad = lane >> 4;

    // A fragments: direct global -> registers, f32 -> bf16 in-reg.
    bf16x8 afrag[2][4];
#pragma unroll
    for (int rt = 0; rt < 2; ++rt) {
        int row = rowBase + w * 32 + rt * 16 + l15;
        const float* src = x + (size_t)row * 128 + quad * 8;
        if (row < M) {
#pragma unroll
            for (int kt = 0; kt < 4; ++kt) {
                float4 f0 = *(const float4*)(src + kt * 32);
                float4 f1 = *(const float4*)(src + kt * 32 + 4);
                afrag[rt][kt] = cvt8(f0, f1);
            }
        } else {
#pragma unroll
            for (int kt = 0; kt < 4; ++kt) {
                bf16x8 z;
#pragma unroll
                for (int q = 0; q < 8; ++q) z[q] = 0;
                afrag[rt][kt] = z;
            }
        }
    }

    // stage B inline from W1 [k][n] f32 -> Bs[n][k] bf16 (L2-resident reads)
#pragma unroll
    for (int i = 0; i < 8; ++i) {
        int idx = t + i * 256;
        int nn = idx >> 4;
        int c8 = (idx & 15) * 8;
        unsigned short tmp[8];
#pragma unroll
        for (int j = 0; j < 8; ++j) tmp[j] = tobf16(W1[(c8 + j) * 128 + nn]);
        *(uint4*)(&Bs[nn * 136 + c8]) = *(uint4*)tmp;
    }
    __syncthreads();

    f32x4 acc[2][8] = {};
    const unsigned short* bp = &Bs[l15 * 136 + quad * 8];

#pragma unroll
    for (int kt = 0; kt < 4; ++kt) {
#pragma unroll
        for (int ct = 0; ct < 8; ++ct) {
            bf16x8 bb = *(const bf16x8*)(bp + ct * 16 * 136 + kt * 32);
            // swapped operands: lane holds row=l15, cols=quad*4+reg
            acc[0][ct] = __builtin_amdgcn_mfma_f32_16x16x32_bf16(bb, afrag[0][kt], acc[0][ct], 0, 0, 0);
            acc[1][ct] = __builtin_amdgcn_mfma_f32_16x16x32_bf16(bb, afrag[1][kt], acc[1][ct], 0, 0, 0);
        }
    }

#pragma unroll
    for (int rt = 0; rt < 2; ++rt) {
        int row = rowBase + w * 32 + rt * 16 + l15;
        if (row < M) {
            unsigned short* dst = hs1 + (size_t)row * 128 + quad * 4;
#pragma unroll
            for (int ct = 0; ct < 8; ++ct) {
                uint2 pv;
                pv.x = pack2(acc[rt][ct][0], acc[rt][ct][1]);
                pv.y = pack2(acc[rt][ct][2], acc[rt][ct][3]);
                *(uint2*)(dst + ct * 16) = pv;
            }
        }
    }
}

// ---------------- per-bucket count/scan/fill ----------------

__global__ __launch_bounds__(256)
void build_k(const int* __restrict__ cursor, const int* __restrict__ store,
             float* __restrict__ dinv, int* __restrict__ offsets,
             int* __restrict__ csr, int M, int nbuck) {
    __shared__ int eds[CAPB];
    __shared__ int cnts[BN];
    __shared__ int offs[BN];
    __shared__ int ps[256];
    __shared__ int sgbase;

    int b = blockIdx.x, t = threadIdx.x;

    int cv = (t < nbuck) ? min(cursor[t], CAPB) : 0;
    ps[t] = cv;
    __syncthreads();
    for (int off = 1; off < 256; off <<= 1) {
        int v = (t >= off) ? ps[t - off] : 0;
        __syncthreads();
        ps[t] += v;
        __syncthreads();
    }
    if (t == b) sgbase = ps[t] - cv;
    if (b == nbuck - 1 && t == nbuck - 1) offsets[M] = ps[t];
    __syncthreads();
    int gbase = sgbase;
    int nE = min(cursor[b], CAPB);

    for (int i = t; i < nE; i += 256) eds[i] = store[b * CAPB + i];
    for (int l = t; l < BN; l += 256) cnts[l] = 0;
    __syncthreads();

    for (int i = t; i < nE; i += 256) atomicAdd(&cnts[eds[i] & (BN - 1)], 1);
    __syncthreads();

    int a0 = cnts[2 * t], a1 = cnts[2 * t + 1];
    int pair = a0 + a1;
    ps[t] = pair;
    __syncthreads();
    for (int off = 1; off < 256; off <<= 1) {
        int v = (t >= off) ? ps[t - off] : 0;
        __syncthreads();
        ps[t] += v;
        __syncthreads();
    }
    int excl = ps[t] - pair;
    offs[2 * t] = excl;
    offs[2 * t + 1] = excl + a0;
    __syncthreads();

    int node0 = b * BN;
    for (int l = t; l < BN; l += 256) {
        int node = node0 + l;
        if (node < M) {
            dinv[node] = rsqrtf(1.0f + (float)cnts[l]);
            offsets[node] = gbase + offs[l];
        }
    }
    __syncthreads();

    for (int i = t; i < nE; i += 256) {
        int pk = eds[i];
        int pos = atomicAdd(&offs[pk & (BN - 1)], 1);
        csr[gbase + pos] = pk >> 9;
    }
}

// ---------------- fused: aggregate(hs1)+bias+ReLU -> LDS -> GEMM2 ----------------
// 512 threads / 32-node tiles (3125 blocks). Bs staged inline from W2 f32
// (transpose-convert, L2-hit -> no init kernel). Gather: 8-wide fully-
// predicated (clamped index, zero weight), MLP=8, no serial tail.
// MFMA swapped -> packed uint2 stores.

__global__ __launch_bounds__(512)
void agg_gemm2_k(const unsigned short* __restrict__ hs1, const int* __restrict__ offsets,
                 const int* __restrict__ csr, const float* __restrict__ dinv,
                 const float* __restrict__ b1, const float* __restrict__ W2,
                 unsigned short* __restrict__ hs2, int M) {
    __shared__ __align__(16) unsigned short As[32 * 136];    //  8.7 KB
    __shared__ __align__(16) unsigned short Bs[64 * 136];    // 17.4 KB

    int t = threadIdx.x;
    const int rowBase = blockIdx.x * 32;

    // stage Bs inline from W2 [k=128][n=64] f32 -> Bs[n][k] bf16
#pragma unroll
    for (int i = 0; i < 2; ++i) {
        int idx = t + i * 512;
        int nn = idx >> 4;
        int c8 = (idx & 15) * 8;
        unsigned short tmp[8];
#pragma unroll
        for (int j = 0; j < 8; ++j) tmp[j] = tobf16(W2[(c8 + j) * 64 + nn]);
        *(uint4*)(&Bs[nn * 136 + c8]) = *(uint4*)tmp;
    }

    const uint4* rows = (const uint4*)hs1;
    const int f8 = t & 15;
    const int r = t >> 4;                 // 0..31 node slot
    const int node = rowBase + r;

    uint4 ov = make_uint4(0, 0, 0, 0);
    if (node < M) {
        float a[8] = {0, 0, 0, 0, 0, 0, 0, 0};
        float dvi = dinv[node];
        acc8f(a, rows[(size_t)node * 16 + f8], dvi);   // self loop
        int k = offsets[node], end = offsets[node + 1];
        while (k < end) {
            int e1 = end - 1;
            int s0 = csr[k];
            int s1 = csr[min(k + 1, e1)];
            int s2 = csr[min(k + 2, e1)];
            int s3 = csr[min(k + 3, e1)];
            int s4 = csr[min(k + 4, e1)];
            int s5 = csr[min(k + 5, e1)];
            int s6 = csr[min(k + 6, e1)];
            int s7 = csr[min(k + 7, e1)];
            uint4 v0 = rows[(size_t)s0 * 16 + f8];
            uint4 v1 = rows[(size_t)s1 * 16 + f8];
            uint4 v2 = rows[(size_t)s2 * 16 + f8];
            uint4 v3 = rows[(size_t)s3 * 16 + f8];
            uint4 v4 = rows[(size_t)s4 * 16 + f8];
            uint4 v5 = rows[(size_t)s5 * 16 + f8];
            uint4 v6 = rows[(size_t)s6 * 16 + f8];
            uint4 v7 = rows[(size_t)s7 * 16 + f8];
            float d0 = dinv[s0];
            float d1 = (k + 1 < end) ? dinv[s1] : 0.f;
            float d2 = (k + 2 < end) ? dinv[s2] : 0.f;
            float d3 = (k + 3 < end) ? dinv[s3] : 0.f;
            float d4 = (k + 4 < end) ? dinv[s4] : 0.f;
            float d5 = (k + 5 < end) ? dinv[s5] : 0.f;
            float d6 = (k + 6 < end) ? dinv[s6] : 0.f;
            float d7 = (k + 7 < end) ? dinv[s7] : 0.f;
            acc8f(a, v0, d0); acc8f(a, v1, d1);
            acc8f(a, v2, d2); acc8f(a, v3, d3);
            acc8f(a, v4, d4); acc8f(a, v5, d5);
            acc8f(a, v6, d6); acc8f(a, v7, d7);
            k += 8;
        }
        const float* bpf = b1 + f8 * 8;
        float4 bA = *(const float4*)bpf;
        float4 bB = *(const float4*)(bpf + 4);
        float r0 = fmaxf(fmaf(a[0], dvi, bA.x), 0.f);
        float r1 = fmaxf(fmaf(a[1], dvi, bA.y), 0.f);
        float r2 = fmaxf(fmaf(a[2], dvi, bA.z), 0.f);
        float r3 = fmaxf(fmaf(a[3], dvi, bA.w), 0.f);
        float r4 = fmaxf(fmaf(a[4], dvi, bB.x), 0.f);
        float r5 = fmaxf(fmaf(a[5], dvi, bB.y), 0.f);
        float r6 = fmaxf(fmaf(a[6], dvi, bB.z), 0.f);
        float r7 = fmaxf(fmaf(a[7], dvi, bB.w), 0.f);
        ov.x = pack2(r0, r1); ov.y = pack2(r2, r3);
        ov.z = pack2(r4, r5); ov.w = pack2(r6, r7);
    }
    *(uint4*)(&As[r * 136 + f8 * 8]) = ov;
    __syncthreads();

    // MFMA: wave w (0..7) -> row tile rt = w>>2, col tile ct = w&3
    const int lane = t & 63;
    const int w = t >> 6;
    const int rt = w >> 2;
    const int ct = w & 3;
    const int l15 = lane & 15;
    const int quad = lane >> 4;

    f32x4 acc = {};
    const unsigned short* ap = &As[(rt * 16 + l15) * 136 + quad * 8];
    const unsigned short* bp = &Bs[(ct * 16 + l15) * 136 + quad * 8];
#pragma unroll
    for (int kt = 0; kt < 4; ++kt) {
        bf16x8 av = *(const bf16x8*)(ap + kt * 32);
        bf16x8 bb = *(const bf16x8*)(bp + kt * 32);
        // swapped: lane holds node row = rt*16+l15, cols = ct*16+quad*4+reg
        acc = __builtin_amdgcn_mfma_f32_16x16x32_bf16(bb, av, acc, 0, 0, 0);
    }
    int row = rowBase + rt * 16 + l15;
    if (row < M) {
        uint2 pv;
        pv.x = pack2(acc[0], acc[1]);
        pv.y = pack2(acc[2], acc[3]);
        *(uint2*)(hs2 + (size_t)row * 64 + ct * 16 + quad * 4) = pv;
    }
}

// ---------------- gather-aggregate layer2 + bias + log_softmax (F=64) ----------------
// 8-wide fully-predicated gather (no serial tail, MLP=8).

__global__ __launch_bounds__(256)
void gather_lsm_k(const unsigned short* __restrict__ hs, const int* __restrict__ offsets,
                  const int* __restrict__ csr, const float* __restrict__ dinv,
                  const float* __restrict__ bias, float* __restrict__ out, int n) {
    int t = threadIdx.x;
    int node = blockIdx.x * 32 + (t >> 3);
    int f8 = t & 7;
    if (node >= n) return;
    const uint4* rows = (const uint4*)hs;
    float a[8] = {0, 0, 0, 0, 0, 0, 0, 0};
    float dvi = dinv[node];
    acc8f(a, rows[(size_t)node * 8 + f8], dvi);
    int k = offsets[node], end = offsets[node + 1];
    while (k < end) {
        int e1 = end - 1;
        int s0 = csr[k];
        int s1 = csr[min(k + 1, e1)];
        int s2 = csr[min(k + 2, e1)];
        int s3 = csr[min(k + 3, e1)];
        int s4 = csr[min(k + 4, e1)];
        int s5 = csr[min(k + 5, e1)];
        int s6 = csr[min(k + 6, e1)];
        int s7 = csr[min(k + 7, e1)];
        uint4 v0 = rows[(size_t)s0 * 8 + f8];
        uint4 v1 = rows[(size_t)s1 * 8 + f8];
        uint4 v2 = rows[(size_t)s2 * 8 + f8];
        uint4 v3 = rows[(size_t)s3 * 8 + f8];
        uint4 v4 = rows[(size_t)s4 * 8 + f8];
        uint4 v5 = rows[(size_t)s5 * 8 + f8];
        uint4 v6 = rows[(size_t)s6 * 8 + f8];
        uint4 v7 = rows[(size_t)s7 * 8 + f8];
        float d0 = dinv[s0];
        float d1 = (k + 1 < end) ? dinv[s1] : 0.f;
        float d2 = (k + 2 < end) ? dinv[s2] : 0.f;
        float d3 = (k + 3 < end) ? dinv[s3] : 0.f;
        float d4 = (k + 4 < end) ? dinv[s4] : 0.f;
        float d5 = (k + 5 < end) ? dinv[s5] : 0.f;
        float d6 = (k + 6 < end) ? dinv[s6] : 0.f;
        float d7 = (k + 7 < end) ? dinv[s7] : 0.f;
        acc8f(a, v0, d0); acc8f(a, v1, d1);
        acc8f(a, v2, d2); acc8f(a, v3, d3);
        acc8f(a, v4, d4); acc8f(a, v5, d5);
        acc8f(a, v6, d6); acc8f(a, v7, d7);
        k += 8;
    }

    const float* bp = bias + f8 * 8;
    float4 bA = *(const float4*)bp;
    float4 bB = *(const float4*)(bp + 4);
    float v0 = fmaf(a[0], dvi, bA.x), v1 = fmaf(a[1], dvi, bA.y);
    float v2 = fmaf(a[2], dvi, bA.z), v3 = fmaf(a[3], dvi, bA.w);
    float v4 = fmaf(a[4], dvi, bB.x), v5 = fmaf(a[5], dvi, bB.y);
    float v6 = fmaf(a[6], dvi, bB.z), v7 = fmaf(a[7], dvi, bB.w);

    float m = fmaxf(fmaxf(fmaxf(v0, v1), fmaxf(v2, v3)), fmaxf(fmaxf(v4, v5), fmaxf(v6, v7)));
#pragma unroll
    for (int off = 1; off < 8; off <<= 1) m = fmaxf(m, __shfl_xor(m, off, 8));
    float e = expf(v0 - m) + expf(v1 - m) + expf(v2 - m) + expf(v3 - m)
            + expf(v4 - m) + expf(v5 - m) + expf(v6 - m) + expf(v7 - m);
#pragma unroll
    for (int off = 1; off < 8; off <<= 1) e += __shfl_xor(e, off, 8);
    float l = m + logf(e);

    float* op = out + (size_t)node * 64 + f8 * 8;
    *(float4*)op       = make_float4(v0 - l, v1 - l, v2 - l, v3 - l);
    *(float4*)(op + 4) = make_float4(v4 - l, v5 - l, v6 - l, v7 - l);
}

// ---------------- launch ----------------

extern "C" void kernel_launch(void* const* d_in, const int* in_sizes, int n_in,
                              void* d_out, int out_size, void* d_ws, size_t ws_size,
                              hipStream_t stream) {
    const float* x  = (const float*)d_in[0];
    const int*   eg = (const int*)d_in[1];
    const float* W1 = (const float*)d_in[2];
    const float* b1 = (const float*)d_in[3];
    const float* W2 = (const float*)d_in[4];
    const float* b2 = (const float*)d_in[5];
    float* out = (float*)d_out;

    const int M = in_sizes[0] / 128;       // 100000
    const int E = in_sizes[1] / 2;         // 640000
    const int* esrc = eg;
    const int* edst = eg + E;
    const int NBUCK = (M + BN - 1) / BN;        // 196
    const int nbin  = (E + CHUNK - 1) / CHUNK;  // 157

    // workspace carve-up
    int* cursor  = (int*)d_ws;                             // [256]
    int* store   = cursor + 256;                           // [NBUCK*CAPB]
    int* offsets = store + (size_t)NBUCK * CAPB;           // [M+1]
    int* csr     = offsets + M + 1;                        // [E]
    uintptr_t p = (uintptr_t)(csr + E);
    p = (p + 255) & ~(uintptr_t)255;
    float* dinv = (float*)p;                               // [M]
    p = (uintptr_t)(dinv + M);
    p = (p + 255) & ~(uintptr_t)255;
    unsigned short* hs1 = (unsigned short*)p;              // [M*128] bf16
    unsigned short* hs2 = hs1 + (size_t)M * 128;           // [M*64]  bf16

    const int gb1 = (M + 127) / 128;       // 782

    hipMemsetAsync(cursor, 0, 256 * sizeof(int), stream);
    bin_gemm1_k<<<gb1 + nbin, 256, 0, stream>>>(x, W1, hs1, M, esrc, edst,
                                                cursor, store, E, nbin, NBUCK);
    build_k<<<NBUCK, 256, 0, stream>>>(cursor, store, dinv, offsets, csr, M, NBUCK);
    agg_gemm2_k<<<(M + 31) / 32, 512, 0, stream>>>(hs1, offsets, csr, dinv, b1, W2, hs2, M);
    gather_lsm_k<<<(M + 31) / 32, 256, 0, stream>>>(hs2, offsets, csr, dinv, b2, out, M);
}

// Round 9
// 182.919 us; speedup vs baseline: 1.3080x; 1.3080x over previous
//
#include <hip/hip_runtime.h>
#include <cstddef>
#include <cstdint>

typedef __attribute__((ext_vector_type(8))) short bf16x8;
typedef __attribute__((ext_vector_type(4))) float f32x4;

constexpr int BN    = 512;    // nodes per bucket
constexpr int CAPB  = 4096;   // per-bucket store capacity (mean 3265, +14 sigma)
constexpr int CHUNK = 4096;   // edges per bin block

__device__ __forceinline__ unsigned short tobf16(float f) {
    unsigned int u = __float_as_uint(f);
    u += 0x7fffu + ((u >> 16) & 1u);   // round to nearest even
    return (unsigned short)(u >> 16);
}
__device__ __forceinline__ float blo(unsigned int u) { return __uint_as_float(u << 16); }
__device__ __forceinline__ float bhi(unsigned int u) { return __uint_as_float(u & 0xffff0000u); }
__device__ __forceinline__ unsigned int pack2(float lo, float hi) {
    return (unsigned int)tobf16(lo) | ((unsigned int)tobf16(hi) << 16);
}
// a[k] += s * row[k]
__device__ __forceinline__ void acc8f(float* a, uint4 v, float s) {
    a[0] = fmaf(s, blo(v.x), a[0]); a[1] = fmaf(s, bhi(v.x), a[1]);
    a[2] = fmaf(s, blo(v.y), a[2]); a[3] = fmaf(s, bhi(v.y), a[3]);
    a[4] = fmaf(s, blo(v.z), a[4]); a[5] = fmaf(s, bhi(v.z), a[5]);
    a[6] = fmaf(s, blo(v.w), a[6]); a[7] = fmaf(s, bhi(v.w), a[7]);
}
__device__ __forceinline__ bf16x8 cvt8(float4 f0, float4 f1) {
    bf16x8 v;
    v[0] = (short)tobf16(f0.x); v[1] = (short)tobf16(f0.y);
    v[2] = (short)tobf16(f0.z); v[3] = (short)tobf16(f0.w);
    v[4] = (short)tobf16(f1.x); v[5] = (short)tobf16(f1.y);
    v[6] = (short)tobf16(f1.z); v[7] = (short)tobf16(f1.w);
    return v;
}

// ---------------- init: zero cursor + convert/transpose weights ----------------
// (Pre-transposed W1T/W2T are essential: inline transposed staging of f32
// weights costs ~25M scalar L2 requests and halves gather BW — round 8.)

__global__ __launch_bounds__(256)
void init_k(int* __restrict__ cursor,
            const float* __restrict__ W1, unsigned short* __restrict__ W1T,
            const float* __restrict__ W2, unsigned short* __restrict__ W2T) {
    int b = blockIdx.x, t = threadIdx.x;
    if (b == 96) { cursor[t] = 0; return; }
    int idx = b * 256 + t;                 // 24576 total
    if (idx < 16384) {                     // W1 [128x128] -> W1T[n][k]
        int k = idx >> 7, n = idx & 127;
        W1T[n * 128 + k] = tobf16(W1[idx]);
    } else {                               // W2 [128x64] -> W2T[n][k]
        int j = idx - 16384;
        int k = j >> 6, n = j & 63;
        W2T[n * 128 + k] = tobf16(W2[j]);
    }
}

// ---------------- fused: edge binning + gemm1 (no dinv) ----------------
// Bin branch: LDS counting-sort by bucket -> coalesced run-writes to store.
// GEMM branch: A direct global->reg, LDS holds only B, swapped-operand MFMA,
// packed uint2 epilogue.

__global__ __launch_bounds__(256)
void bin_gemm1_k(const float* __restrict__ x, const unsigned short* __restrict__ W1T,
                 unsigned short* __restrict__ hs1, int M,
                 const int* __restrict__ esrc, const int* __restrict__ edst,
                 int* __restrict__ cursor, int* __restrict__ store, int E,
                 int nbin, int nbuck) {
    __shared__ __align__(16) unsigned char smem[34816];
    int b = blockIdx.x, t = threadIdx.x;

    if (b < nbin) {
        // ---- bin branch: histogram -> scan -> LDS sort -> coalesced store ----
        int* sorted = (int*)smem;                   // [4096] 16KB
        int* bkt    = (int*)(smem + 16384);         // [4096] 16KB
        int* comb   = (int*)(smem + 32768);         // [256]  hist -> combined base
        int* ps     = (int*)(smem + 33792);         // [256]  scan -> excl

        comb[t] = 0;                                // hist
        __syncthreads();
        int base = b * CHUNK;
        int nloc = min(CHUNK, E - base);
        int lh[16], bk_[16], pk_[16];
#pragma unroll
        for (int j = 0; j < 16; ++j) {
            int i = j * 256 + t;
            if (i < nloc) {
                int s = esrc[base + i], d = edst[base + i];
                bk_[j] = d >> 9;
                pk_[j] = (s << 9) | (d & (BN - 1));
                lh[j] = atomicAdd(&comb[bk_[j]], 1);
            }
        }
        __syncthreads();
        int hv = comb[t];
        ps[t] = hv;
        __syncthreads();
        for (int off = 1; off < 256; off <<= 1) {
            int v = (t >= off) ? ps[t - off] : 0;
            __syncthreads();
            ps[t] += v;
            __syncthreads();
        }
        int excl = ps[t] - hv;
        ps[t] = excl;                               // own-slot rewrite, no race
        int g = 0;
        if (t < nbuck && hv) g = atomicAdd(&cursor[t], hv);
        comb[t] = t * CAPB + g - excl;              // store base minus local base
        __syncthreads();
#pragma unroll
        for (int j = 0; j < 16; ++j) {
            int i = j * 256 + t;
            if (i < nloc) {
                int lp = ps[bk_[j]] + lh[j];
                sorted[lp] = pk_[j];
                bkt[lp] = bk_[j];
            }
        }
        __syncthreads();
#pragma unroll
        for (int j = 0; j < 16; ++j) {
            int i = j * 256 + t;
            if (i < nloc) {
                int bk = bkt[i];
                int idx = comb[bk] + i;             // consecutive i -> consecutive idx per bucket run
                if (idx - bk * CAPB < CAPB) store[idx] = sorted[i];
            }
        }
        return;
    }

    // ---- gemm1 branch ----
    unsigned short* Bs = (unsigned short*)smem;             // 128*136 bf16
    const int rowBase = (b - nbin) * 128;

    const int lane = t & 63;
    const int w = t >> 6;
    const int l15 = lane & 15;
    const int quad = lane >> 4;

    // A fragments: direct global -> registers, f32 -> bf16 in-reg.
    bf16x8 afrag[2][4];
#pragma unroll
    for (int rt = 0; rt < 2; ++rt) {
        int row = rowBase + w * 32 + rt * 16 + l15;
        const float* src = x + (size_t)row * 128 + quad * 8;
        if (row < M) {
#pragma unroll
            for (int kt = 0; kt < 4; ++kt) {
                float4 f0 = *(const float4*)(src + kt * 32);
                float4 f1 = *(const float4*)(src + kt * 32 + 4);
                afrag[rt][kt] = cvt8(f0, f1);
            }
        } else {
#pragma unroll
            for (int kt = 0; kt < 4; ++kt) {
                bf16x8 z;
#pragma unroll
                for (int q = 0; q < 8; ++q) z[q] = 0;
                afrag[rt][kt] = z;
            }
        }
    }

    // stage B: 128 rows x 16 uint4 = 2048 over 256 threads
#pragma unroll
    for (int i = 0; i < 8; ++i) {
        int idx = t + i * 256;
        int nn = idx >> 4;
        int c8 = (idx & 15) * 8;
        *(uint4*)(&Bs[nn * 136 + c8]) = *(const uint4*)(W1T + nn * 128 + c8);
    }
    __syncthreads();

    f32x4 acc[2][8] = {};
    const unsigned short* bp = &Bs[l15 * 136 + quad * 8];

#pragma unroll
    for (int kt = 0; kt < 4; ++kt) {
#pragma unroll
        for (int ct = 0; ct < 8; ++ct) {
            bf16x8 bb = *(const bf16x8*)(bp + ct * 16 * 136 + kt * 32);
            // swapped operands: lane holds row=l15, cols=quad*4+reg
            acc[0][ct] = __builtin_amdgcn_mfma_f32_16x16x32_bf16(bb, afrag[0][kt], acc[0][ct], 0, 0, 0);
            acc[1][ct] = __builtin_amdgcn_mfma_f32_16x16x32_bf16(bb, afrag[1][kt], acc[1][ct], 0, 0, 0);
        }
    }

#pragma unroll
    for (int rt = 0; rt < 2; ++rt) {
        int row = rowBase + w * 32 + rt * 16 + l15;
        if (row < M) {
            unsigned short* dst = hs1 + (size_t)row * 128 + quad * 4;
#pragma unroll
            for (int ct = 0; ct < 8; ++ct) {
                uint2 pv;
                pv.x = pack2(acc[rt][ct][0], acc[rt][ct][1]);
                pv.y = pack2(acc[rt][ct][2], acc[rt][ct][3]);
                *(uint2*)(dst + ct * 16) = pv;
            }
        }
    }
}

// ---------------- per-bucket count/scan/fill ----------------

__global__ __launch_bounds__(256)
void build_k(const int* __restrict__ cursor, const int* __restrict__ store,
             float* __restrict__ dinv, int* __restrict__ offsets,
             int* __restrict__ csr, int M, int nbuck) {
    __shared__ int eds[CAPB];
    __shared__ int cnts[BN];
    __shared__ int offs[BN];
    __shared__ int ps[256];
    __shared__ int sgbase;

    int b = blockIdx.x, t = threadIdx.x;

    int cv = (t < nbuck) ? min(cursor[t], CAPB) : 0;
    ps[t] = cv;
    __syncthreads();
    for (int off = 1; off < 256; off <<= 1) {
        int v = (t >= off) ? ps[t - off] : 0;
        __syncthreads();
        ps[t] += v;
        __syncthreads();
    }
    if (t == b) sgbase = ps[t] - cv;
    if (b == nbuck - 1 && t == nbuck - 1) offsets[M] = ps[t];
    __syncthreads();
    int gbase = sgbase;
    int nE = min(cursor[b], CAPB);

    for (int i = t; i < nE; i += 256) eds[i] = store[b * CAPB + i];
    for (int l = t; l < BN; l += 256) cnts[l] = 0;
    __syncthreads();

    for (int i = t; i < nE; i += 256) atomicAdd(&cnts[eds[i] & (BN - 1)], 1);
    __syncthreads();

    int a0 = cnts[2 * t], a1 = cnts[2 * t + 1];
    int pair = a0 + a1;
    ps[t] = pair;
    __syncthreads();
    for (int off = 1; off < 256; off <<= 1) {
        int v = (t >= off) ? ps[t - off] : 0;
        __syncthreads();
        ps[t] += v;
        __syncthreads();
    }
    int excl = ps[t] - pair;
    offs[2 * t] = excl;
    offs[2 * t + 1] = excl + a0;
    __syncthreads();

    int node0 = b * BN;
    for (int l = t; l < BN; l += 256) {
        int node = node0 + l;
        if (node < M) {
            dinv[node] = rsqrtf(1.0f + (float)cnts[l]);
            offsets[node] = gbase + offs[l];
        }
    }
    __syncthreads();

    for (int i = t; i < nE; i += 256) {
        int pk = eds[i];
        int pos = atomicAdd(&offs[pk & (BN - 1)], 1);
        csr[gbase + pos] = pk >> 9;
    }
}

// ---------------- fused: aggregate(hs1)+bias+ReLU -> LDS -> GEMM2 ----------------
// 256 threads / 16-node tiles (6250 blocks): LDS 21.8 KB -> 7 blocks/CU =
// 28 waves/CU. Gather: 8-wide fully-predicated -> no serial tail, MLP = 8.

__global__ __launch_bounds__(256)
void agg_gemm2_k(const unsigned short* __restrict__ hs1, const int* __restrict__ offsets,
                 const int* __restrict__ csr, const float* __restrict__ dinv,
                 const float* __restrict__ b1, const unsigned short* __restrict__ W2T,
                 unsigned short* __restrict__ hs2, int M) {
    __shared__ __align__(16) unsigned short As[16 * 136];    //  4.3 KB
    __shared__ __align__(16) unsigned short Bs[64 * 136];    // 17.4 KB

    int t = threadIdx.x;
    const int rowBase = blockIdx.x * 16;

    // stage Bs: 64 rows x 16 uint4 = 1024 over 256 threads
#pragma unroll
    for (int i = 0; i < 4; ++i) {
        int idx = t + i * 256;
        int nn = idx >> 4;
        int c8 = (idx & 15) * 8;
        *(uint4*)(&Bs[nn * 136 + c8]) = *(const uint4*)(W2T + nn * 128 + c8);
    }

    const uint4* rows = (const uint4*)hs1;
    const int f8 = t & 15;
    const int r = t >> 4;                 // 0..15 node slot
    const int node = rowBase + r;

    uint4 ov = make_uint4(0, 0, 0, 0);
    if (node < M) {
        float a[8] = {0, 0, 0, 0, 0, 0, 0, 0};
        float dvi = dinv[node];
        acc8f(a, rows[(size_t)node * 16 + f8], dvi);   // self loop
        int k = offsets[node], end = offsets[node + 1];
        while (k < end) {
            int e1 = end - 1;
            int s0 = csr[k];
            int s1 = csr[min(k + 1, e1)];
            int s2 = csr[min(k + 2, e1)];
            int s3 = csr[min(k + 3, e1)];
            int s4 = csr[min(k + 4, e1)];
            int s5 = csr[min(k + 5, e1)];
            int s6 = csr[min(k + 6, e1)];
            int s7 = csr[min(k + 7, e1)];
            uint4 v0 = rows[(size_t)s0 * 16 + f8];
            uint4 v1 = rows[(size_t)s1 * 16 + f8];
            uint4 v2 = rows[(size_t)s2 * 16 + f8];
            uint4 v3 = rows[(size_t)s3 * 16 + f8];
            uint4 v4 = rows[(size_t)s4 * 16 + f8];
            uint4 v5 = rows[(size_t)s5 * 16 + f8];
            uint4 v6 = rows[(size_t)s6 * 16 + f8];
            uint4 v7 = rows[(size_t)s7 * 16 + f8];
            float d0 = dinv[s0];
            float d1 = (k + 1 < end) ? dinv[s1] : 0.f;
            float d2 = (k + 2 < end) ? dinv[s2] : 0.f;
            float d3 = (k + 3 < end) ? dinv[s3] : 0.f;
            float d4 = (k + 4 < end) ? dinv[s4] : 0.f;
            float d5 = (k + 5 < end) ? dinv[s5] : 0.f;
            float d6 = (k + 6 < end) ? dinv[s6] : 0.f;
            float d7 = (k + 7 < end) ? dinv[s7] : 0.f;
            acc8f(a, v0, d0); acc8f(a, v1, d1);
            acc8f(a, v2, d2); acc8f(a, v3, d3);
            acc8f(a, v4, d4); acc8f(a, v5, d5);
            acc8f(a, v6, d6); acc8f(a, v7, d7);
            k += 8;
        }
        const float* bpf = b1 + f8 * 8;
        float4 bA = *(const float4*)bpf;
        float4 bB = *(const float4*)(bpf + 4);
        float r0 = fmaxf(fmaf(a[0], dvi, bA.x), 0.f);
        float r1 = fmaxf(fmaf(a[1], dvi, bA.y), 0.f);
        float r2 = fmaxf(fmaf(a[2], dvi, bA.z), 0.f);
        float r3 = fmaxf(fmaf(a[3], dvi, bA.w), 0.f);
        float r4 = fmaxf(fmaf(a[4], dvi, bB.x), 0.f);
        float r5 = fmaxf(fmaf(a[5], dvi, bB.y), 0.f);
        float r6 = fmaxf(fmaf(a[6], dvi, bB.z), 0.f);
        float r7 = fmaxf(fmaf(a[7], dvi, bB.w), 0.f);
        ov.x = pack2(r0, r1); ov.y = pack2(r2, r3);
        ov.z = pack2(r4, r5); ov.w = pack2(r6, r7);
    }
    *(uint4*)(&As[r * 136 + f8 * 8]) = ov;
    __syncthreads();

    // MFMA: wave w -> col tile ct = w (16 rows x 64 cols total)
    const int lane = t & 63;
    const int ct = t >> 6;         // 0..3
    const int l15 = lane & 15;
    const int quad = lane >> 4;

    f32x4 acc = {};
    const unsigned short* ap = &As[l15 * 136 + quad * 8];
    const unsigned short* bp = &Bs[(ct * 16 + l15) * 136 + quad * 8];
#pragma unroll
    for (int kt = 0; kt < 4; ++kt) {
        bf16x8 av = *(const bf16x8*)(ap + kt * 32);
        bf16x8 bb = *(const bf16x8*)(bp + kt * 32);
        // swapped: lane holds node row = l15, cols = ct*16+quad*4+reg
        acc = __builtin_amdgcn_mfma_f32_16x16x32_bf16(bb, av, acc, 0, 0, 0);
    }
    int row = rowBase + l15;
    if (row < M) {
        uint2 pv;
        pv.x = pack2(acc[0], acc[1]);
        pv.y = pack2(acc[2], acc[3]);
        *(uint2*)(hs2 + (size_t)row * 64 + ct * 16 + quad * 4) = pv;
    }
}

// ---------------- gather-aggregate layer2 + bias + log_softmax (F=64) ----------------
// 8-wide fully-predicated gather (no serial tail, MLP=8).

__global__ __launch_bounds__(256)
void gather_lsm_k(const unsigned short* __restrict__ hs, const int* __restrict__ offsets,
                  const int* __restrict__ csr, const float* __restrict__ dinv,
                  const float* __restrict__ bias, float* __restrict__ out, int n) {
    int t = threadIdx.x;
    int node = blockIdx.x * 32 + (t >> 3);
    int f8 = t & 7;
    if (node >= n) return;
    const uint4* rows = (const uint4*)hs;
    float a[8] = {0, 0, 0, 0, 0, 0, 0, 0};
    float dvi = dinv[node];
    acc8f(a, rows[(size_t)node * 8 + f8], dvi);
    int k = offsets[node], end = offsets[node + 1];
    while (k < end) {
        int e1 = end - 1;
        int s0 = csr[k];
        int s1 = csr[min(k + 1, e1)];
        int s2 = csr[min(k + 2, e1)];
        int s3 = csr[min(k + 3, e1)];
        int s4 = csr[min(k + 4, e1)];
        int s5 = csr[min(k + 5, e1)];
        int s6 = csr[min(k + 6, e1)];
        int s7 = csr[min(k + 7, e1)];
        uint4 v0 = rows[(size_t)s0 * 8 + f8];
        uint4 v1 = rows[(size_t)s1 * 8 + f8];
        uint4 v2 = rows[(size_t)s2 * 8 + f8];
        uint4 v3 = rows[(size_t)s3 * 8 + f8];
        uint4 v4 = rows[(size_t)s4 * 8 + f8];
        uint4 v5 = rows[(size_t)s5 * 8 + f8];
        uint4 v6 = rows[(size_t)s6 * 8 + f8];
        uint4 v7 = rows[(size_t)s7 * 8 + f8];
        float d0 = dinv[s0];
        float d1 = (k + 1 < end) ? dinv[s1] : 0.f;
        float d2 = (k + 2 < end) ? dinv[s2] : 0.f;
        float d3 = (k + 3 < end) ? dinv[s3] : 0.f;
        float d4 = (k + 4 < end) ? dinv[s4] : 0.f;
        float d5 = (k + 5 < end) ? dinv[s5] : 0.f;
        float d6 = (k + 6 < end) ? dinv[s6] : 0.f;
        float d7 = (k + 7 < end) ? dinv[s7] : 0.f;
        acc8f(a, v0, d0); acc8f(a, v1, d1);
        acc8f(a, v2, d2); acc8f(a, v3, d3);
        acc8f(a, v4, d4); acc8f(a, v5, d5);
        acc8f(a, v6, d6); acc8f(a, v7, d7);
        k += 8;
    }

    const float* bp = bias + f8 * 8;
    float4 bA = *(const float4*)bp;
    float4 bB = *(const float4*)(bp + 4);
    float v0 = fmaf(a[0], dvi, bA.x), v1 = fmaf(a[1], dvi, bA.y);
    float v2 = fmaf(a[2], dvi, bA.z), v3 = fmaf(a[3], dvi, bA.w);
    float v4 = fmaf(a[4], dvi, bB.x), v5 = fmaf(a[5], dvi, bB.y);
    float v6 = fmaf(a[6], dvi, bB.z), v7 = fmaf(a[7], dvi, bB.w);

    float m = fmaxf(fmaxf(fmaxf(v0, v1), fmaxf(v2, v3)), fmaxf(fmaxf(v4, v5), fmaxf(v6, v7)));
#pragma unroll
    for (int off = 1; off < 8; off <<= 1) m = fmaxf(m, __shfl_xor(m, off, 8));
    float e = expf(v0 - m) + expf(v1 - m) + expf(v2 - m) + expf(v3 - m)
            + expf(v4 - m) + expf(v5 - m) + expf(v6 - m) + expf(v7 - m);
#pragma unroll
    for (int off = 1; off < 8; off <<= 1) e += __shfl_xor(e, off, 8);
    float l = m + logf(e);

    float* op = out + (size_t)node * 64 + f8 * 8;
    *(float4*)op       = make_float4(v0 - l, v1 - l, v2 - l, v3 - l);
    *(float4*)(op + 4) = make_float4(v4 - l, v5 - l, v6 - l, v7 - l);
}

// ---------------- launch ----------------

extern "C" void kernel_launch(void* const* d_in, const int* in_sizes, int n_in,
                              void* d_out, int out_size, void* d_ws, size_t ws_size,
                              hipStream_t stream) {
    const float* x  = (const float*)d_in[0];
    const int*   eg = (const int*)d_in[1];
    const float* W1 = (const float*)d_in[2];
    const float* b1 = (const float*)d_in[3];
    const float* W2 = (const float*)d_in[4];
    const float* b2 = (const float*)d_in[5];
    float* out = (float*)d_out;

    const int M = in_sizes[0] / 128;       // 100000
    const int E = in_sizes[1] / 2;         // 640000
    const int* esrc = eg;
    const int* edst = eg + E;
    const int NBUCK = (M + BN - 1) / BN;        // 196
    const int nbin  = (E + CHUNK - 1) / CHUNK;  // 157

    // workspace carve-up
    int* cursor  = (int*)d_ws;                             // [256]
    int* store   = cursor + 256;                           // [NBUCK*CAPB]
    int* offsets = store + (size_t)NBUCK * CAPB;           // [M+1]
    int* csr     = offsets + M + 1;                        // [E]
    uintptr_t p = (uintptr_t)(csr + E);
    p = (p + 255) & ~(uintptr_t)255;
    float* dinv = (float*)p;                               // [M]
    p = (uintptr_t)(dinv + M);
    p = (p + 255) & ~(uintptr_t)255;
    unsigned short* hs1 = (unsigned short*)p;              // [M*128] bf16
    unsigned short* hs2 = hs1 + (size_t)M * 128;           // [M*64]  bf16
    unsigned short* W1T = hs2 + (size_t)M * 64;            // [128*128]
    unsigned short* W2T = W1T + 128 * 128;                 // [64*128]

    const int gb1 = (M + 127) / 128;       // 782

    init_k<<<97, 256, 0, stream>>>(cursor, W1, W1T, W2, W2T);
    bin_gemm1_k<<<gb1 + nbin, 256, 0, stream>>>(x, W1T, hs1, M, esrc, edst,
                                                cursor, store, E, nbin, NBUCK);
    build_k<<<NBUCK, 256, 0, stream>>>(cursor, store, dinv, offsets, csr, M, NBUCK);
    agg_gemm2_k<<<(M + 15) / 16, 256, 0, stream>>>(hs1, offsets, csr, dinv, b1, W2T, hs2, M);
    gather_lsm_k<<<(M + 31) / 32, 256, 0, stream>>>(hs2, offsets, csr, dinv, b2, out, M);
}